// Round 1
// baseline (300.771 us; speedup 1.0000x reference)
//
#include <hip/hip_runtime.h>

typedef __bf16 bf16x8 __attribute__((ext_vector_type(8)));
typedef float f32x4 __attribute__((ext_vector_type(4)));

typedef const unsigned int __attribute__((address_space(1)))* gas_p;
typedef unsigned int __attribute__((address_space(3)))* las_p;

__device__ __forceinline__ void gload_lds16(const void* g, void* l) {
  __builtin_amdgcn_global_load_lds((gas_p)g, (las_p)l, 16, 0, 0);
}

__device__ __forceinline__ unsigned short f2bf(float f) {
  union { float f; unsigned int u; } x; x.f = f;
  unsigned int r = x.u + 0x7fffu + ((x.u >> 16) & 1u);
  return (unsigned short)(r >> 16);
}
__device__ __forceinline__ float bf2f(unsigned short h) {
  union { unsigned int u; float f; } x; x.u = (unsigned int)h << 16;
  return x.f;
}
__device__ __forceinline__ float elu1(float x) {
  return x > 0.f ? x + 1.f : __expf(x);
}
__device__ __forceinline__ f32x4 mfma16(bf16x8 a, bf16x8 b, f32x4 c) {
  return __builtin_amdgcn_mfma_f32_16x16x32_bf16(a, b, c, 0, 0, 0);
}

// ---------------- converts ----------------

__global__ __launch_bounds__(256) void k_cvt_x(const float* __restrict__ x,
                                               unsigned short* __restrict__ xb, int n) {
  int i = (blockIdx.x * 256 + threadIdx.x) * 4;
  const int stride = gridDim.x * 256 * 4;
  for (; i < n; i += stride) {
    float4 v = *(const float4*)(x + i);
    union { unsigned short u[4]; uint2 q; } pk;
    pk.u[0] = f2bf(v.x); pk.u[1] = f2bf(v.y); pk.u[2] = f2bf(v.z); pk.u[3] = f2bf(v.w);
    *(uint2*)(xb + i) = pk.q;
  }
}

// w[R][Cc] (f32) -> wT[Cc][R] (bf16)
__global__ __launch_bounds__(256) void k_cvt_t(const float* __restrict__ w,
                                               unsigned short* __restrict__ wT,
                                               int R, int Cc) {
  __shared__ float t[32][33];
  const int j0 = blockIdx.x * 32, i0 = blockIdx.y * 32;
  const int tx = threadIdx.x & 31, ty = threadIdx.x >> 5;
#pragma unroll
  for (int k = 0; k < 4; ++k)
    t[ty + 8 * k][tx] = w[(size_t)(i0 + ty + 8 * k) * Cc + j0 + tx];
  __syncthreads();
#pragma unroll
  for (int k = 0; k < 4; ++k)
    wT[(size_t)(j0 + ty + 8 * k) * R + i0 + tx] = f2bf(t[tx][ty + 8 * k]);
}

// ---------------- GEMM1: qkv = x @ w_qkv, fused elu+1 + layout scatter ----------------
// A: xb[16384][1024], BT: wqkvT[3072][1024]
// outputs: qb[16384][1024] (elu+1), kT[bh=64][d=64][n=4096] (elu+1), vT same layout

__global__ __launch_bounds__(256) void k_gemm_qkv(const unsigned short* __restrict__ A,
                                                  const unsigned short* __restrict__ BT,
                                                  unsigned short* __restrict__ qb,
                                                  unsigned short* __restrict__ kT,
                                                  unsigned short* __restrict__ vT) {
  __shared__ unsigned short As[128 * 64];
  __shared__ unsigned short Bs[128 * 64];
  const int K = 1024;
  const int tid = threadIdx.x, lane = tid & 63, wave = tid >> 6;
  const int bm0 = blockIdx.y << 7, bn0 = blockIdx.x << 7;
  const int wr = (wave >> 1) << 6, wc = (wave & 1) << 6;
  const int lrow = lane >> 3, lcol = (lane & 7) << 3;
  f32x4 acc[4][4] = {};

  for (int ks = 0; ks < K; ks += 64) {
    __syncthreads();
#pragma unroll
    for (int i = 0; i < 4; ++i) {
      const int c = i * 4 + wave;
      gload_lds16(A + (size_t)(bm0 + c * 8 + lrow) * K + ks + lcol, &As[c * 512]);
      gload_lds16(BT + (size_t)(bn0 + c * 8 + lrow) * K + ks + lcol, &Bs[c * 512]);
    }
    __syncthreads();
    const int ko = (lane >> 4) << 3;
    const int ar = wr + (lane & 15), br = wc + (lane & 15);
#pragma unroll
    for (int kk = 0; kk < 2; ++kk) {
      bf16x8 a[4], b[4];
#pragma unroll
      for (int m = 0; m < 4; ++m) a[m] = *(const bf16x8*)&As[(ar + m * 16) * 64 + ko + kk * 32];
#pragma unroll
      for (int n = 0; n < 4; ++n) b[n] = *(const bf16x8*)&Bs[(br + n * 16) * 64 + ko + kk * 32];
#pragma unroll
      for (int m = 0; m < 4; ++m)
#pragma unroll
        for (int n = 0; n < 4; ++n)
          acc[m][n] = mfma16(a[m], b[n], acc[m][n]);
    }
  }

  const int r0 = bm0 + wr + ((lane >> 4) << 2);
  const int c0 = bn0 + wc + (lane & 15);
#pragma unroll
  for (int n = 0; n < 4; ++n) {
    const int col = c0 + n * 16;
    const int reg = col >> 10;  // 0=q 1=k 2=v  (uniform per tile)
#pragma unroll
    for (int m = 0; m < 4; ++m) {
      const int rb = r0 + m * 16;
      if (reg == 0) {
#pragma unroll
        for (int i = 0; i < 4; ++i)
          qb[(size_t)(rb + i) * 1024 + col] = f2bf(elu1(acc[m][n][i]));
      } else {
        const int jj = col & 1023;
        const int h = jj >> 6, d = jj & 63;
        const int b_ = rb >> 12, n_ = rb & 4095;
        union { unsigned short u[4]; uint2 q; } pk;
        if (reg == 1) {
#pragma unroll
          for (int i = 0; i < 4; ++i) pk.u[i] = f2bf(elu1(acc[m][n][i]));
        } else {
#pragma unroll
          for (int i = 0; i < 4; ++i) pk.u[i] = f2bf(acc[m][n][i]);
        }
        unsigned short* dst = (reg == 1) ? kT : vT;
        *(uint2*)(dst + ((size_t)((b_ * 16 + h) * 64 + d) * 4096 + n_)) = pk.q;
      }
    }
  }
}

// ---------------- sum_k: row sums of kT (one wave per (bh,d) row) ----------------

__device__ __forceinline__ float bfsum2(unsigned int w) {
  union { unsigned int u; float f; } a, b;
  a.u = w << 16; b.u = w & 0xffff0000u;
  return a.f + b.f;
}

__global__ __launch_bounds__(256) void k_sumk(const unsigned short* __restrict__ kT,
                                              float* __restrict__ sumk) {
  const int row = (blockIdx.x << 2) + (threadIdx.x >> 6);
  const int lane = threadIdx.x & 63;
  const unsigned short* p = kT + (size_t)row * 4096;
  float s = 0.f;
#pragma unroll
  for (int i = 0; i < 8; ++i) {
    uint4 v = *(const uint4*)(p + (i * 64 + lane) * 8);
    s += bfsum2(v.x) + bfsum2(v.y) + bfsum2(v.z) + bfsum2(v.w);
  }
#pragma unroll
  for (int off = 32; off > 0; off >>= 1) s += __shfl_down(s, off);
  if (lane == 0) sumk[row] = s;
}

// ---------------- kv partial: per (bh, n-chunk of 512) MFMA K^T @ V ----------------
// kvp[blk=bh*8+ch][d=64][e=64] fp32

__global__ __launch_bounds__(256) void k_kvpart(const unsigned short* __restrict__ kT,
                                                const unsigned short* __restrict__ vT,
                                                float* __restrict__ kvp) {
  __shared__ unsigned short Ks[64 * 64];
  __shared__ unsigned short Vs[64 * 64];
  const int blk = blockIdx.x;
  const int bh = blk >> 3, ch = blk & 7;
  const int tid = threadIdx.x, lane = tid & 63, wave = tid >> 6;
  const unsigned short* kb = kT + (size_t)bh * 64 * 4096;
  const unsigned short* vb = vT + (size_t)bh * 64 * 4096;
  const int n0 = ch * 512;
  const int lrow = lane >> 3, lcol = (lane & 7) << 3;
  f32x4 acc[4] = {};

  for (int ks = 0; ks < 512; ks += 64) {
    __syncthreads();
#pragma unroll
    for (int i = 0; i < 2; ++i) {
      const int c = i * 4 + wave;  // 8 chunks of 8 rows
      gload_lds16(kb + (size_t)(c * 8 + lrow) * 4096 + n0 + ks + lcol, &Ks[c * 512]);
      gload_lds16(vb + (size_t)(c * 8 + lrow) * 4096 + n0 + ks + lcol, &Vs[c * 512]);
    }
    __syncthreads();
    const int ko = (lane >> 4) << 3;
    const int ar = wave * 16 + (lane & 15);
#pragma unroll
    for (int kk = 0; kk < 2; ++kk) {
      bf16x8 a = *(const bf16x8*)&Ks[ar * 64 + ko + kk * 32];
#pragma unroll
      for (int n = 0; n < 4; ++n) {
        bf16x8 bv = *(const bf16x8*)&Vs[(n * 16 + (lane & 15)) * 64 + ko + kk * 32];
        acc[n] = mfma16(a, bv, acc[n]);
      }
    }
  }
  float* dst = kvp + (size_t)blk * 64 * 64;
  const int d0 = wave * 16 + ((lane >> 4) << 2);
#pragma unroll
  for (int n = 0; n < 4; ++n)
#pragma unroll
    for (int i = 0; i < 4; ++i)
      dst[(d0 + i) * 64 + n * 16 + (lane & 15)] = acc[n][i];
}

// ---------------- kv reduce: sum 8 partials, write B^T panel [80][64] per bh ----------------
// rows 0..63: kvT[e][d] = kv[d][e]; row 64: sum_k[d]; rows 65..79: 0

__global__ __launch_bounds__(256) void k_kvred(const float* __restrict__ kvp,
                                               const float* __restrict__ sumk,
                                               unsigned short* __restrict__ kvsk) {
  const int bh = blockIdx.x, tid = threadIdx.x;
  const float* src = kvp + (size_t)bh * 8 * 4096;
  unsigned short* dst = kvsk + (size_t)bh * 80 * 64;
#pragma unroll
  for (int it = 0; it < 16; ++it) {
    const int idx = tid + it * 256;  // e*64+d
    const int e = idx >> 6, d = idx & 63;
    float s = 0.f;
#pragma unroll
    for (int c = 0; c < 8; ++c) s += src[c * 4096 + d * 64 + e];
    dst[idx] = f2bf(s);
  }
#pragma unroll
  for (int it = 0; it < 4; ++it) {
    const int idx = tid + it * 256;  // rows 64..79
    const int e2 = idx >> 6, d = idx & 63;
    float v = (e2 == 0) ? sumk[bh * 64 + d] : 0.f;
    dst[64 * 64 + idx] = f2bf(v);
  }
}

// ---------------- numerator + denominator + divide: y = (q@kv)/(q@sum_k) ----------------
// qb[16384][1024]; kvsk[bh][80][64]; yb[16384][1024]

__global__ __launch_bounds__(256) void k_numer(const unsigned short* __restrict__ qb,
                                               const unsigned short* __restrict__ kvsk,
                                               unsigned short* __restrict__ yb) {
  __shared__ unsigned short Bs[80 * 64];
  const int bh = blockIdx.y;
  const int b = bh >> 4, h = bh & 15;
  const int n0 = blockIdx.x << 7;
  const int tid = threadIdx.x, lane = tid & 63, wave = tid >> 6;
  {
    const uint4* src = (const uint4*)(kvsk + (size_t)bh * 80 * 64);
    uint4* dst = (uint4*)Bs;
    for (int i = tid; i < 640; i += 256) dst[i] = src[i];
  }
  __syncthreads();

  const int ko = (lane >> 4) << 3;
  f32x4 acc[2][5] = {};
  const unsigned short* qrow =
      qb + (size_t)(b * 4096 + n0 + wave * 32 + (lane & 15)) * 1024 + h * 64;
#pragma unroll
  for (int kk = 0; kk < 2; ++kk) {
    bf16x8 a[2], bb[5];
#pragma unroll
    for (int m = 0; m < 2; ++m)
      a[m] = *(const bf16x8*)(qrow + (size_t)m * 16 * 1024 + ko + kk * 32);
#pragma unroll
    for (int n = 0; n < 5; ++n)
      bb[n] = *(const bf16x8*)&Bs[(n * 16 + (lane & 15)) * 64 + ko + kk * 32];
#pragma unroll
    for (int m = 0; m < 2; ++m)
#pragma unroll
      for (int n = 0; n < 5; ++n)
        acc[m][n] = mfma16(a[m], bb[n], acc[m][n]);
  }

  const int rbase = b * 4096 + n0 + wave * 32 + ((lane >> 4) << 2);
#pragma unroll
  for (int m = 0; m < 2; ++m) {
    f32x4 inv;
#pragma unroll
    for (int i = 0; i < 4; ++i) {
      float den = __shfl(acc[m][4][i], lane & 48);
      inv[i] = __builtin_amdgcn_rcpf(den);
    }
#pragma unroll
    for (int n = 0; n < 4; ++n) {
      const int col = h * 64 + n * 16 + (lane & 15);
#pragma unroll
      for (int i = 0; i < 4; ++i)
        yb[(size_t)(rbase + m * 16 + i) * 1024 + col] = f2bf(acc[m][n][i] * inv[i]);
    }
  }
}

// ---------------- GEMM2: out = y @ w_proj + b_proj (fp32 out) ----------------

__global__ __launch_bounds__(256) void k_gemm_proj(const unsigned short* __restrict__ A,
                                                   const unsigned short* __restrict__ BT,
                                                   const float* __restrict__ bias,
                                                   float* __restrict__ out) {
  __shared__ unsigned short As[128 * 64];
  __shared__ unsigned short Bs[128 * 64];
  const int K = 1024;
  const int tid = threadIdx.x, lane = tid & 63, wave = tid >> 6;
  const int bm0 = blockIdx.y << 7, bn0 = blockIdx.x << 7;
  const int wr = (wave >> 1) << 6, wc = (wave & 1) << 6;
  const int lrow = lane >> 3, lcol = (lane & 7) << 3;
  f32x4 acc[4][4] = {};

  for (int ks = 0; ks < K; ks += 64) {
    __syncthreads();
#pragma unroll
    for (int i = 0; i < 4; ++i) {
      const int c = i * 4 + wave;
      gload_lds16(A + (size_t)(bm0 + c * 8 + lrow) * K + ks + lcol, &As[c * 512]);
      gload_lds16(BT + (size_t)(bn0 + c * 8 + lrow) * K + ks + lcol, &Bs[c * 512]);
    }
    __syncthreads();
    const int ko = (lane >> 4) << 3;
    const int ar = wr + (lane & 15), br = wc + (lane & 15);
#pragma unroll
    for (int kk = 0; kk < 2; ++kk) {
      bf16x8 a[4], b[4];
#pragma unroll
      for (int m = 0; m < 4; ++m) a[m] = *(const bf16x8*)&As[(ar + m * 16) * 64 + ko + kk * 32];
#pragma unroll
      for (int n = 0; n < 4; ++n) b[n] = *(const bf16x8*)&Bs[(br + n * 16) * 64 + ko + kk * 32];
#pragma unroll
      for (int m = 0; m < 4; ++m)
#pragma unroll
        for (int n = 0; n < 4; ++n)
          acc[m][n] = mfma16(a[m], b[n], acc[m][n]);
    }
  }

  const int r0 = bm0 + wr + ((lane >> 4) << 2);
  const int c0 = bn0 + wc + (lane & 15);
#pragma unroll
  for (int n = 0; n < 4; ++n) {
    const int col = c0 + n * 16;
    const float bc = bias[col];
#pragma unroll
    for (int m = 0; m < 4; ++m) {
      const int rb = r0 + m * 16;
#pragma unroll
      for (int i = 0; i < 4; ++i)
        out[(size_t)(rb + i) * 1024 + col] = acc[m][n][i] + bc;
    }
  }
}

// ---------------- launch ----------------

extern "C" void kernel_launch(void* const* d_in, const int* in_sizes, int n_in,
                              void* d_out, int out_size, void* d_ws, size_t ws_size,
                              hipStream_t stream) {
  const float* x = (const float*)d_in[0];
  const float* w_qkv = (const float*)d_in[1];
  const float* w_proj = (const float*)d_in[2];
  const float* b_proj = (const float*)d_in[3];
  float* out = (float*)d_out;
  char* ws = (char*)d_ws;

  unsigned short* xb = (unsigned short*)(ws);                   // 33,554,432 B (reused as yb)
  unsigned short* wqkvT = (unsigned short*)(ws + 33554432);     //  6,291,456 B
  unsigned short* wprojT = (unsigned short*)(ws + 39845888);    //  2,097,152 B
  unsigned short* qb = (unsigned short*)(ws + 41943040);        // 33,554,432 B
  unsigned short* kT = (unsigned short*)(ws + 75497472);        // 33,554,432 B
  unsigned short* vT = (unsigned short*)(ws + 109051904);       // 33,554,432 B
  float* kvp = (float*)(ws + 142606336);                        //  8,388,608 B
  float* sumk = (float*)(ws + 150994944);                       //     16,384 B
  unsigned short* kvsk = (unsigned short*)(ws + 151011328);     //    655,360 B
  unsigned short* yb = xb;  // xb dead after GEMM1

  k_cvt_x<<<2048, 256, 0, stream>>>(x, xb, 4 * 4096 * 1024);
  k_cvt_t<<<dim3(96, 32), 256, 0, stream>>>(w_qkv, wqkvT, 1024, 3072);
  k_cvt_t<<<dim3(32, 32), 256, 0, stream>>>(w_proj, wprojT, 1024, 1024);
  k_gemm_qkv<<<dim3(24, 128), 256, 0, stream>>>(xb, wqkvT, qb, kT, vT);
  k_sumk<<<1024, 256, 0, stream>>>(kT, sumk);
  k_kvpart<<<512, 256, 0, stream>>>(kT, vT, kvp);
  k_kvred<<<64, 256, 0, stream>>>(kvp, sumk, kvsk);
  k_numer<<<dim3(32, 64), 256, 0, stream>>>(qb, kvsk, yb);
  k_gemm_proj<<<dim3(8, 128), 256, 0, stream>>>(yb, wprojT, b_proj, out);
}

// Round 2
// 235.955 us; speedup vs baseline: 1.2747x; 1.2747x over previous
//
#include <hip/hip_runtime.h>

typedef __bf16 bf16x8 __attribute__((ext_vector_type(8)));
typedef float f32x4 __attribute__((ext_vector_type(4)));

typedef const unsigned int __attribute__((address_space(1)))* gas_p;
typedef unsigned int __attribute__((address_space(3)))* las_p;

__device__ __forceinline__ void gload_lds16(const void* g, void* l) {
  __builtin_amdgcn_global_load_lds((gas_p)g, (las_p)l, 16, 0, 0);
}

__device__ __forceinline__ unsigned short f2bf(float f) {
  union { float f; unsigned int u; } x; x.f = f;
  unsigned int r = x.u + 0x7fffu + ((x.u >> 16) & 1u);
  return (unsigned short)(r >> 16);
}
__device__ __forceinline__ float elu1(float x) {
  return x > 0.f ? x + 1.f : __expf(x);
}
__device__ __forceinline__ f32x4 mfma16(bf16x8 a, bf16x8 b, f32x4 c) {
  return __builtin_amdgcn_mfma_f32_16x16x32_bf16(a, b, c, 0, 0, 0);
}

#define BAR() __builtin_amdgcn_s_barrier()
#define VMW4() asm volatile("s_waitcnt vmcnt(4)" ::: "memory")

// ---------------- converts ----------------

__global__ __launch_bounds__(256) void k_cvt_x(const float* __restrict__ x,
                                               unsigned short* __restrict__ xb, int n) {
  int i = (blockIdx.x * 256 + threadIdx.x) * 4;
  const int stride = gridDim.x * 256 * 4;
  for (; i < n; i += stride) {
    float4 v = *(const float4*)(x + i);
    union { unsigned short u[4]; uint2 q; } pk;
    pk.u[0] = f2bf(v.x); pk.u[1] = f2bf(v.y); pk.u[2] = f2bf(v.z); pk.u[3] = f2bf(v.w);
    *(uint2*)(xb + i) = pk.q;
  }
}

__global__ __launch_bounds__(256) void k_cvt_t(const float* __restrict__ w,
                                               unsigned short* __restrict__ wT,
                                               int R, int Cc) {
  __shared__ float t[32][33];
  const int j0 = blockIdx.x * 32, i0 = blockIdx.y * 32;
  const int tx = threadIdx.x & 31, ty = threadIdx.x >> 5;
#pragma unroll
  for (int k = 0; k < 4; ++k)
    t[ty + 8 * k][tx] = w[(size_t)(i0 + ty + 8 * k) * Cc + j0 + tx];
  __syncthreads();
#pragma unroll
  for (int k = 0; k < 4; ++k)
    wT[(size_t)(j0 + ty + 8 * k) * R + i0 + tx] = f2bf(t[tx][ty + 8 * k]);
}

// ---------------- 256x256 8-phase GEMM (K=1024, BK=64, K-half LDS layout) ----------------
// EPI=0: qkv epilogue (elu+1 on q,k; scatter k,v to [bh][d][n]); EPI=1: proj (+bias, f32 out)

template <int EPI>
__global__ __launch_bounds__(512, 2) void k_gemm256(
    const unsigned short* __restrict__ A, const unsigned short* __restrict__ BT, int NBX,
    unsigned short* __restrict__ qb, unsigned short* __restrict__ kT,
    unsigned short* __restrict__ vT, const float* __restrict__ bias,
    float* __restrict__ out) {
  extern __shared__ unsigned short lds[];
  unsigned short* Asb = lds;           // [buf*2+h][256*32] elems  (buf: 0/16384, h: +8192)
  unsigned short* Bsb = lds + 32768;

  const int tid = threadIdx.x, lane = tid & 63, wave = tid >> 6;
  const int wm = wave >> 2, wn = wave & 3;
  int bid = blockIdx.x;
  { const int cpx = (int)gridDim.x >> 3; bid = (bid & 7) * cpx + (bid >> 3); }
  const int bx = bid % NBX, by = bid / NBX;
  const size_t bm0 = (size_t)by << 8, bn0 = (size_t)bx << 8;

  // staging: thread covers row = j*128 + wave*16 + lane/4, col = (lane&3)*8 within [256][32] half
  const int srow = (wave << 4) + (lane >> 2);
  const int scol = (lane & 3) << 3;
  const unsigned short* Ag0 = A + (bm0 + srow) * 1024 + scol;
  const unsigned short* Bg0 = BT + (bn0 + srow) * 1024 + scol;
  unsigned short* Al0 = Asb + (wave << 9);
  unsigned short* Bl0 = Bsb + (wave << 9);

#define STAGE_A(OBH, KT)                                          \
  do {                                                            \
    const unsigned short* g_ = Ag0 + ((KT) << 6) + (OBH_K);       \
    unsigned short* l_ = Al0 + (OBH);                             \
    gload_lds16(g_, l_);                                          \
    gload_lds16(g_ + 128 * 1024, l_ + 4096);                      \
  } while (0)
#define STAGE_B(OBH, KT)                                          \
  do {                                                            \
    const unsigned short* g_ = Bg0 + ((KT) << 6) + (OBH_K);       \
    unsigned short* l_ = Bl0 + (OBH);                             \
    gload_lds16(g_, l_);                                          \
    gload_lds16(g_ + 128 * 1024, l_ + 4096);                      \
  } while (0)

  const int q8 = (lane >> 4) << 3;                 // k-window within 32
  const int ar_base = (wm << 7) + (lane & 15);     // + rh*64 + mi*16
  const int br_base = (wn << 6) + (lane & 15);     // + n*16

  f32x4 acc[8][4] = {};  // [m = rh*4+mi][n]

  // prologue: stage K-tile 0 into buffer 0 in consumption order A(h0),B(h0),A(h1),B(h1)
  {
#define OBH_K 0
    STAGE_A(0, 0);
    STAGE_B(0, 0);
#undef OBH_K
#define OBH_K 32
    STAGE_A(8192, 0);
    STAGE_B(8192, 0);
#undef OBH_K
  }
  VMW4();  // A(h0), B(h0) landed
  BAR();

  for (int kt = 0; kt < 16; ++kt) {
    const int ob = (kt & 1) << 14;       // this K-tile's buffer elem offset
    const int obn = ob ^ 16384;          // next K-tile's buffer
    const int ktn = (kt < 15) ? kt + 1 : 15;
    bf16x8 af[4], bfr[4];

    // ---- P0: kk=0, rh=0 (+ stage A(next,h0)) ----
#pragma unroll
    for (int mi = 0; mi < 4; ++mi)
      af[mi] = *(const bf16x8*)&Asb[ob + ((ar_base + mi * 16) << 5) + q8];
#pragma unroll
    for (int n = 0; n < 4; ++n)
      bfr[n] = *(const bf16x8*)&Bsb[ob + ((br_base + n * 16) << 5) + q8];
#define OBH_K 0
    STAGE_A(obn, ktn);
#undef OBH_K
    BAR();
    __builtin_amdgcn_s_setprio(1);
#pragma unroll
    for (int mi = 0; mi < 4; ++mi)
#pragma unroll
      for (int n = 0; n < 4; ++n) acc[mi][n] = mfma16(af[mi], bfr[n], acc[mi][n]);
    __builtin_amdgcn_s_setprio(0);
    BAR();

    // ---- P1: kk=0, rh=1 (+ stage B(next,h0)) ----
#pragma unroll
    for (int mi = 0; mi < 4; ++mi)
      af[mi] = *(const bf16x8*)&Asb[ob + ((ar_base + 64 + mi * 16) << 5) + q8];
#define OBH_K 0
    STAGE_B(obn, ktn);
#undef OBH_K
    BAR();
    __builtin_amdgcn_s_setprio(1);
#pragma unroll
    for (int mi = 0; mi < 4; ++mi)
#pragma unroll
      for (int n = 0; n < 4; ++n) acc[4 + mi][n] = mfma16(af[mi], bfr[n], acc[4 + mi][n]);
    __builtin_amdgcn_s_setprio(0);
    VMW4();  // A(cur,h1), B(cur,h1) landed
    BAR();

    // ---- P2: kk=1, rh=0 (+ stage A(next,h1)) ----
#pragma unroll
    for (int mi = 0; mi < 4; ++mi)
      af[mi] = *(const bf16x8*)&Asb[ob + 8192 + ((ar_base + mi * 16) << 5) + q8];
#pragma unroll
    for (int n = 0; n < 4; ++n)
      bfr[n] = *(const bf16x8*)&Bsb[ob + 8192 + ((br_base + n * 16) << 5) + q8];
#define OBH_K 32
    STAGE_A(obn + 8192, ktn);
#undef OBH_K
    BAR();
    __builtin_amdgcn_s_setprio(1);
#pragma unroll
    for (int mi = 0; mi < 4; ++mi)
#pragma unroll
      for (int n = 0; n < 4; ++n) acc[mi][n] = mfma16(af[mi], bfr[n], acc[mi][n]);
    __builtin_amdgcn_s_setprio(0);
    BAR();

    // ---- P3: kk=1, rh=1 (+ stage B(next,h1)) ----
#pragma unroll
    for (int mi = 0; mi < 4; ++mi)
      af[mi] = *(const bf16x8*)&Asb[ob + 8192 + ((ar_base + 64 + mi * 16) << 5) + q8];
#define OBH_K 32
    STAGE_B(obn + 8192, ktn);
#undef OBH_K
    BAR();
    __builtin_amdgcn_s_setprio(1);
#pragma unroll
    for (int mi = 0; mi < 4; ++mi)
#pragma unroll
      for (int n = 0; n < 4; ++n) acc[4 + mi][n] = mfma16(af[mi], bfr[n], acc[4 + mi][n]);
    __builtin_amdgcn_s_setprio(0);
    VMW4();  // A(next,h0), B(next,h0) landed
    BAR();
  }

  // ---- epilogue ----
  const int rbase = (int)bm0 + (wm << 7) + ((lane >> 4) << 2);
  const int cbase = (int)bn0 + (wn << 6) + (lane & 15);
  if constexpr (EPI == 0) {
    const int reg3 = (int)(bn0 >> 10);  // 0=q 1=k 2=v, uniform per block
#pragma unroll
    for (int m = 0; m < 8; ++m) {
      const int rb = rbase + m * 16;
#pragma unroll
      for (int n = 0; n < 4; ++n) {
        const int col = cbase + n * 16;
        if (reg3 == 0) {
#pragma unroll
          for (int i = 0; i < 4; ++i)
            qb[(size_t)(rb + i) * 1024 + col] = f2bf(elu1(acc[m][n][i]));
        } else {
          const int jc = col & 1023, h = jc >> 6, d = jc & 63;
          const int b_ = rb >> 12, n_ = rb & 4095;
          union { unsigned short u[4]; uint2 q; } pk;
          if (reg3 == 1) {
#pragma unroll
            for (int i = 0; i < 4; ++i) pk.u[i] = f2bf(elu1(acc[m][n][i]));
          } else {
#pragma unroll
            for (int i = 0; i < 4; ++i) pk.u[i] = f2bf(acc[m][n][i]);
          }
          unsigned short* dst = (reg3 == 1) ? kT : vT;
          *(uint2*)(dst + ((size_t)((b_ * 16 + h) * 64 + d) * 4096 + n_)) = pk.q;
        }
      }
    }
  } else {
#pragma unroll
    for (int n = 0; n < 4; ++n) {
      const int col = cbase + n * 16;
      const float bc = bias[col];
#pragma unroll
      for (int m = 0; m < 8; ++m) {
        const int rb = rbase + m * 16;
#pragma unroll
        for (int i = 0; i < 4; ++i)
          out[(size_t)(rb + i) * 1024 + col] = acc[m][n][i] + bc;
      }
    }
  }
#undef STAGE_A
#undef STAGE_B
}

// ---------------- sum_k ----------------

__device__ __forceinline__ float bfsum2(unsigned int w) {
  union { unsigned int u; float f; } a, b;
  a.u = w << 16; b.u = w & 0xffff0000u;
  return a.f + b.f;
}

__global__ __launch_bounds__(256) void k_sumk(const unsigned short* __restrict__ kT,
                                              float* __restrict__ sumk) {
  const int row = (blockIdx.x << 2) + (threadIdx.x >> 6);
  const int lane = threadIdx.x & 63;
  const unsigned short* p = kT + (size_t)row * 4096;
  float s = 0.f;
#pragma unroll
  for (int i = 0; i < 8; ++i) {
    uint4 v = *(const uint4*)(p + (i * 64 + lane) * 8);
    s += bfsum2(v.x) + bfsum2(v.y) + bfsum2(v.z) + bfsum2(v.w);
  }
#pragma unroll
  for (int off = 32; off > 0; off >>= 1) s += __shfl_down(s, off);
  if (lane == 0) sumk[row] = s;
}

// ---------------- kv partial ----------------

__global__ __launch_bounds__(256) void k_kvpart(const unsigned short* __restrict__ kT,
                                                const unsigned short* __restrict__ vT,
                                                float* __restrict__ kvp) {
  __shared__ unsigned short Ks[64 * 64];
  __shared__ unsigned short Vs[64 * 64];
  const int blk = blockIdx.x;
  const int bh = blk >> 3, ch = blk & 7;
  const int tid = threadIdx.x, lane = tid & 63, wave = tid >> 6;
  const unsigned short* kb = kT + (size_t)bh * 64 * 4096;
  const unsigned short* vb = vT + (size_t)bh * 64 * 4096;
  const int n0 = ch * 512;
  const int lrow = lane >> 3, lcol = (lane & 7) << 3;
  f32x4 acc[4] = {};

  for (int ks = 0; ks < 512; ks += 64) {
    __syncthreads();
#pragma unroll
    for (int i = 0; i < 2; ++i) {
      const int c = i * 4 + wave;
      gload_lds16(kb + (size_t)(c * 8 + lrow) * 4096 + n0 + ks + lcol, &Ks[c * 512]);
      gload_lds16(vb + (size_t)(c * 8 + lrow) * 4096 + n0 + ks + lcol, &Vs[c * 512]);
    }
    __syncthreads();
    const int ko = (lane >> 4) << 3;
    const int ar = wave * 16 + (lane & 15);
#pragma unroll
    for (int kk = 0; kk < 2; ++kk) {
      bf16x8 a = *(const bf16x8*)&Ks[ar * 64 + ko + kk * 32];
#pragma unroll
      for (int n = 0; n < 4; ++n) {
        bf16x8 bv = *(const bf16x8*)&Vs[(n * 16 + (lane & 15)) * 64 + ko + kk * 32];
        acc[n] = mfma16(a, bv, acc[n]);
      }
    }
  }
  float* dst = kvp + (size_t)blk * 64 * 64;
  const int d0 = wave * 16 + ((lane >> 4) << 2);
#pragma unroll
  for (int n = 0; n < 4; ++n)
#pragma unroll
    for (int i = 0; i < 4; ++i)
      dst[(d0 + i) * 64 + n * 16 + (lane & 15)] = acc[n][i];
}

// ---------------- kv reduce ----------------

__global__ __launch_bounds__(256) void k_kvred(const float* __restrict__ kvp,
                                               const float* __restrict__ sumk,
                                               unsigned short* __restrict__ kvsk) {
  const int bh = blockIdx.x, tid = threadIdx.x;
  const float* src = kvp + (size_t)bh * 8 * 4096;
  unsigned short* dst = kvsk + (size_t)bh * 80 * 64;
#pragma unroll
  for (int it = 0; it < 16; ++it) {
    const int idx = tid + it * 256;
    const int e = idx >> 6, d = idx & 63;
    float s = 0.f;
#pragma unroll
    for (int c = 0; c < 8; ++c) s += src[c * 4096 + d * 64 + e];
    dst[idx] = f2bf(s);
  }
#pragma unroll
  for (int it = 0; it < 4; ++it) {
    const int idx = tid + it * 256;
    const int e2 = idx >> 6, d = idx & 63;
    float v = (e2 == 0) ? sumk[bh * 64 + d] : 0.f;
    dst[64 * 64 + idx] = f2bf(v);
  }
}

// ---------------- numerator/denominator/divide ----------------

__global__ __launch_bounds__(256) void k_numer(const unsigned short* __restrict__ qb,
                                               const unsigned short* __restrict__ kvsk,
                                               unsigned short* __restrict__ yb) {
  __shared__ unsigned short Bs[80 * 64];
  const int bh = blockIdx.y;
  const int b = bh >> 4, h = bh & 15;
  const int n0 = blockIdx.x << 7;
  const int tid = threadIdx.x, lane = tid & 63, wave = tid >> 6;
  {
    const uint4* src = (const uint4*)(kvsk + (size_t)bh * 80 * 64);
    uint4* dst = (uint4*)Bs;
    for (int i = tid; i < 640; i += 256) dst[i] = src[i];
  }
  __syncthreads();

  const int ko = (lane >> 4) << 3;
  f32x4 acc[2][5] = {};
  const unsigned short* qrow =
      qb + (size_t)(b * 4096 + n0 + wave * 32 + (lane & 15)) * 1024 + h * 64;
#pragma unroll
  for (int kk = 0; kk < 2; ++kk) {
    bf16x8 a[2], bb[5];
#pragma unroll
    for (int m = 0; m < 2; ++m)
      a[m] = *(const bf16x8*)(qrow + (size_t)m * 16 * 1024 + ko + kk * 32);
#pragma unroll
    for (int n = 0; n < 5; ++n)
      bb[n] = *(const bf16x8*)&Bs[(n * 16 + (lane & 15)) * 64 + ko + kk * 32];
#pragma unroll
    for (int m = 0; m < 2; ++m)
#pragma unroll
      for (int n = 0; n < 5; ++n)
        acc[m][n] = mfma16(a[m], bb[n], acc[m][n]);
  }

  const int rbase = b * 4096 + n0 + wave * 32 + ((lane >> 4) << 2);
#pragma unroll
  for (int m = 0; m < 2; ++m) {
    f32x4 inv;
#pragma unroll
    for (int i = 0; i < 4; ++i) {
      float den = __shfl(acc[m][4][i], lane & 48);
      inv[i] = __builtin_amdgcn_rcpf(den);
    }
#pragma unroll
    for (int n = 0; n < 4; ++n) {
      const int col = h * 64 + n * 16 + (lane & 15);
#pragma unroll
      for (int i = 0; i < 4; ++i)
        yb[(size_t)(rbase + m * 16 + i) * 1024 + col] = f2bf(acc[m][n][i] * inv[i]);
    }
  }
}

// ---------------- launch ----------------

extern "C" void kernel_launch(void* const* d_in, const int* in_sizes, int n_in,
                              void* d_out, int out_size, void* d_ws, size_t ws_size,
                              hipStream_t stream) {
  const float* x = (const float*)d_in[0];
  const float* w_qkv = (const float*)d_in[1];
  const float* w_proj = (const float*)d_in[2];
  const float* b_proj = (const float*)d_in[3];
  float* out = (float*)d_out;
  char* ws = (char*)d_ws;

  unsigned short* xb = (unsigned short*)(ws);                   // 33,554,432 B (reused as yb)
  unsigned short* wqkvT = (unsigned short*)(ws + 33554432);     //  6,291,456 B
  unsigned short* wprojT = (unsigned short*)(ws + 39845888);    //  2,097,152 B
  unsigned short* qb = (unsigned short*)(ws + 41943040);        // 33,554,432 B
  unsigned short* kT = (unsigned short*)(ws + 75497472);        // 33,554,432 B
  unsigned short* vT = (unsigned short*)(ws + 109051904);       // 33,554,432 B
  float* kvp = (float*)(ws + 142606336);                        //  8,388,608 B
  float* sumk = (float*)(ws + 150994944);                       //     16,384 B
  unsigned short* kvsk = (unsigned short*)(ws + 151011328);     //    655,360 B
  unsigned short* yb = xb;

  k_cvt_x<<<2048, 256, 0, stream>>>(x, xb, 4 * 4096 * 1024);
  k_cvt_t<<<dim3(96, 32), 256, 0, stream>>>(w_qkv, wqkvT, 1024, 3072);
  k_cvt_t<<<dim3(32, 32), 256, 0, stream>>>(w_proj, wprojT, 1024, 1024);
  k_gemm256<0><<<768, 512, 131072, stream>>>(xb, wqkvT, 12, qb, kT, vT, nullptr, nullptr);
  k_sumk<<<1024, 256, 0, stream>>>(kT, sumk);
  k_kvpart<<<512, 256, 0, stream>>>(kT, vT, kvp);
  k_kvred<<<64, 256, 0, stream>>>(kvp, sumk, kvsk);
  k_numer<<<dim3(32, 64), 256, 0, stream>>>(qb, kvsk, yb);
  k_gemm256<1><<<256, 512, 131072, stream>>>(yb, wprojT, 4, nullptr, nullptr, nullptr,
                                             b_proj, out);
}

// Round 3
// 222.831 us; speedup vs baseline: 1.3498x; 1.0589x over previous
//
#include <hip/hip_runtime.h>

typedef __bf16 bf16x8 __attribute__((ext_vector_type(8)));
typedef float f32x4 __attribute__((ext_vector_type(4)));

typedef const unsigned int __attribute__((address_space(1)))* gas_p;
typedef unsigned int __attribute__((address_space(3)))* las_p;

__device__ __forceinline__ void gload_lds16(const void* g, void* l) {
  __builtin_amdgcn_global_load_lds((gas_p)g, (las_p)l, 16, 0, 0);
}

__device__ __forceinline__ unsigned short f2bf(float f) {
  union { float f; unsigned int u; } x; x.f = f;
  unsigned int r = x.u + 0x7fffu + ((x.u >> 16) & 1u);
  return (unsigned short)(r >> 16);
}
__device__ __forceinline__ float elu1(float x) {
  return x > 0.f ? x + 1.f : __expf(x);
}
__device__ __forceinline__ f32x4 mfma16(bf16x8 a, bf16x8 b, f32x4 c) {
  return __builtin_amdgcn_mfma_f32_16x16x32_bf16(a, b, c, 0, 0, 0);
}

#define BAR() __builtin_amdgcn_s_barrier()
#define VMW4() asm volatile("s_waitcnt vmcnt(4)" ::: "memory")

// ---------------- converts ----------------

__global__ __launch_bounds__(256) void k_cvt_x(const float* __restrict__ x,
                                               unsigned short* __restrict__ xb, int n) {
  int i = (blockIdx.x * 256 + threadIdx.x) * 4;
  const int stride = gridDim.x * 256 * 4;
  for (; i < n; i += stride) {
    float4 v = *(const float4*)(x + i);
    union { unsigned short u[4]; uint2 q; } pk;
    pk.u[0] = f2bf(v.x); pk.u[1] = f2bf(v.y); pk.u[2] = f2bf(v.z); pk.u[3] = f2bf(v.w);
    *(uint2*)(xb + i) = pk.q;
  }
}

__global__ __launch_bounds__(256) void k_cvt_t(const float* __restrict__ w,
                                               unsigned short* __restrict__ wT,
                                               int R, int Cc) {
  __shared__ float t[32][33];
  const int j0 = blockIdx.x * 32, i0 = blockIdx.y * 32;
  const int tx = threadIdx.x & 31, ty = threadIdx.x >> 5;
#pragma unroll
  for (int k = 0; k < 4; ++k)
    t[ty + 8 * k][tx] = w[(size_t)(i0 + ty + 8 * k) * Cc + j0 + tx];
  __syncthreads();
#pragma unroll
  for (int k = 0; k < 4; ++k)
    wT[(size_t)(j0 + ty + 8 * k) * R + i0 + tx] = f2bf(t[tx][ty + 8 * k]);
}

// ---------------- 256x256 8-phase GEMM (K=1024, BK=64, K-half LDS, T2 swizzle) ----------
// LDS halves are [256 rows][32 K-elems] (64B rows). Swizzle: col_bytes ^= ((row>>1)&3)<<4.
// global_load_lds writes linearly -> inverse-swizzle the GLOBAL source col (rule 21).

template <int EPI>
__global__ __launch_bounds__(512, 2) void k_gemm256(
    const unsigned short* __restrict__ A, const unsigned short* __restrict__ BT, int NBX,
    unsigned short* __restrict__ qb, unsigned short* __restrict__ kT,
    unsigned short* __restrict__ vT, const float* __restrict__ bias,
    float* __restrict__ out) {
  extern __shared__ unsigned short lds[];
  unsigned short* Asb = lds;           // [buf*2+h][256*32] elems  (buf: 0/16384, h: +8192)
  unsigned short* Bsb = lds + 32768;

  const int tid = threadIdx.x, lane = tid & 63, wave = tid >> 6;
  const int wm = wave >> 2, wn = wave & 3;
  int bid = blockIdx.x;
  { const int cpx = (int)gridDim.x >> 3; bid = (bid & 7) * cpx + (bid >> 3); }
  const int bx = bid % NBX, by = bid / NBX;
  const size_t bm0 = (size_t)by << 8, bn0 = (size_t)bx << 8;

  // staging: thread t covers LDS slot t*16B -> row = t>>2, col = (t&3)*8 elems within half.
  // source col pre-swizzled: gscol = col ^ (((row>>1)&3)<<3) elems.
  const int srow = (wave << 4) + (lane >> 2);
  const int gscol = ((lane & 3) << 3) ^ (((srow >> 1) & 3) << 3);
  const unsigned short* Ag0 = A + (bm0 + srow) * 1024 + gscol;
  const unsigned short* Bg0 = BT + (bn0 + srow) * 1024 + gscol;
  unsigned short* Al0 = Asb + (wave << 9);
  unsigned short* Bl0 = Bsb + (wave << 9);

#define STAGE_A(OBH, KT)                                          \
  do {                                                            \
    const unsigned short* g_ = Ag0 + ((KT) << 6) + (OBH_K);       \
    unsigned short* l_ = Al0 + (OBH);                             \
    gload_lds16(g_, l_);                                          \
    gload_lds16(g_ + 128 * 1024, l_ + 4096);                      \
  } while (0)
#define STAGE_B(OBH, KT)                                          \
  do {                                                            \
    const unsigned short* g_ = Bg0 + ((KT) << 6) + (OBH_K);       \
    unsigned short* l_ = Bl0 + (OBH);                             \
    gload_lds16(g_, l_);                                          \
    gload_lds16(g_ + 128 * 1024, l_ + 4096);                      \
  } while (0)

  // fragment reads: row r = ...+(lane&15); swizzled k-offset within 32-elem window
  const int q8 = (((lane >> 4) << 3)) ^ (((lane >> 1) & 3) << 3);
  const int ar_base = (wm << 7) + (lane & 15);     // + rh*64 + mi*16
  const int br_base = (wn << 6) + (lane & 15);     // + n*16

  f32x4 acc[8][4] = {};  // [m = rh*4+mi][n]

  // prologue: stage K-tile 0 into buffer 0 in consumption order A(h0),B(h0),A(h1),B(h1)
  {
#define OBH_K 0
    STAGE_A(0, 0);
    STAGE_B(0, 0);
#undef OBH_K
#define OBH_K 32
    STAGE_A(8192, 0);
    STAGE_B(8192, 0);
#undef OBH_K
  }
  VMW4();  // A(h0), B(h0) landed
  BAR();

  for (int kt = 0; kt < 16; ++kt) {
    const int ob = (kt & 1) << 14;       // this K-tile's buffer elem offset
    const int obn = ob ^ 16384;          // next K-tile's buffer
    const int ktn = (kt < 15) ? kt + 1 : 15;
    bf16x8 af[4], bfr[4];

    // ---- P0: kk=0, rh=0 (+ stage A(next,h0)) ----
#pragma unroll
    for (int mi = 0; mi < 4; ++mi)
      af[mi] = *(const bf16x8*)&Asb[ob + ((ar_base + mi * 16) << 5) + q8];
#pragma unroll
    for (int n = 0; n < 4; ++n)
      bfr[n] = *(const bf16x8*)&Bsb[ob + ((br_base + n * 16) << 5) + q8];
#define OBH_K 0
    STAGE_A(obn, ktn);
#undef OBH_K
    BAR();
    __builtin_amdgcn_s_setprio(1);
#pragma unroll
    for (int mi = 0; mi < 4; ++mi)
#pragma unroll
      for (int n = 0; n < 4; ++n) acc[mi][n] = mfma16(af[mi], bfr[n], acc[mi][n]);
    __builtin_amdgcn_s_setprio(0);
    BAR();

    // ---- P1: kk=0, rh=1 (+ stage B(next,h0)) ----
#pragma unroll
    for (int mi = 0; mi < 4; ++mi)
      af[mi] = *(const bf16x8*)&Asb[ob + ((ar_base + 64 + mi * 16) << 5) + q8];
#define OBH_K 0
    STAGE_B(obn, ktn);
#undef OBH_K
    BAR();
    __builtin_amdgcn_s_setprio(1);
#pragma unroll
    for (int mi = 0; mi < 4; ++mi)
#pragma unroll
      for (int n = 0; n < 4; ++n) acc[4 + mi][n] = mfma16(af[mi], bfr[n], acc[4 + mi][n]);
    __builtin_amdgcn_s_setprio(0);
    VMW4();  // A(cur,h1), B(cur,h1) landed
    BAR();

    // ---- P2: kk=1, rh=0 (+ stage A(next,h1)) ----
#pragma unroll
    for (int mi = 0; mi < 4; ++mi)
      af[mi] = *(const bf16x8*)&Asb[ob + 8192 + ((ar_base + mi * 16) << 5) + q8];
#pragma unroll
    for (int n = 0; n < 4; ++n)
      bfr[n] = *(const bf16x8*)&Bsb[ob + 8192 + ((br_base + n * 16) << 5) + q8];
#define OBH_K 32
    STAGE_A(obn + 8192, ktn);
#undef OBH_K
    BAR();
    __builtin_amdgcn_s_setprio(1);
#pragma unroll
    for (int mi = 0; mi < 4; ++mi)
#pragma unroll
      for (int n = 0; n < 4; ++n) acc[mi][n] = mfma16(af[mi], bfr[n], acc[mi][n]);
    __builtin_amdgcn_s_setprio(0);
    BAR();

    // ---- P3: kk=1, rh=1 (+ stage B(next,h1)) ----
#pragma unroll
    for (int mi = 0; mi < 4; ++mi)
      af[mi] = *(const bf16x8*)&Asb[ob + 8192 + ((ar_base + 64 + mi * 16) << 5) + q8];
#define OBH_K 32
    STAGE_B(obn + 8192, ktn);
#undef OBH_K
    BAR();
    __builtin_amdgcn_s_setprio(1);
#pragma unroll
    for (int mi = 0; mi < 4; ++mi)
#pragma unroll
      for (int n = 0; n < 4; ++n) acc[4 + mi][n] = mfma16(af[mi], bfr[n], acc[4 + mi][n]);
    __builtin_amdgcn_s_setprio(0);
    VMW4();  // A(next,h0), B(next,h0) landed
    BAR();
  }

  // ---- epilogue ----
  const int rbase = (int)bm0 + (wm << 7) + ((lane >> 4) << 2);
  const int cbase = (int)bn0 + (wn << 6) + (lane & 15);
  if constexpr (EPI == 0) {
    const int reg3 = (int)(bn0 >> 10);  // 0=q 1=k 2=v, uniform per block
#pragma unroll
    for (int m = 0; m < 8; ++m) {
      const int rb = rbase + m * 16;
#pragma unroll
      for (int n = 0; n < 4; ++n) {
        const int col = cbase + n * 16;
        if (reg3 == 0) {
#pragma unroll
          for (int i = 0; i < 4; ++i)
            qb[(size_t)(rb + i) * 1024 + col] = f2bf(elu1(acc[m][n][i]));
        } else {
          const int jc = col & 1023, h = jc >> 6, d = jc & 63;
          const int b_ = rb >> 12, n_ = rb & 4095;
          union { unsigned short u[4]; uint2 q; } pk;
          if (reg3 == 1) {
#pragma unroll
            for (int i = 0; i < 4; ++i) pk.u[i] = f2bf(elu1(acc[m][n][i]));
          } else {
#pragma unroll
            for (int i = 0; i < 4; ++i) pk.u[i] = f2bf(acc[m][n][i]);
          }
          unsigned short* dst = (reg3 == 1) ? kT : vT;
          *(uint2*)(dst + ((size_t)((b_ * 16 + h) * 64 + d) * 4096 + n_)) = pk.q;
        }
      }
    }
  } else {
#pragma unroll
    for (int n = 0; n < 4; ++n) {
      const int col = cbase + n * 16;
      const float bc = bias[col];
#pragma unroll
      for (int m = 0; m < 8; ++m) {
        const int rb = rbase + m * 16;
#pragma unroll
        for (int i = 0; i < 4; ++i)
          out[(size_t)(rb + i) * 1024 + col] = acc[m][n][i] + bc;
      }
    }
  }
#undef STAGE_A
#undef STAGE_B
}

// ---------------- kv partial (+ fused sum_k via ones-column) ----------------
// LDS tiles [64 rows][64 elems] = 128B rows; swizzle byte ^= ((row&7)<<4).

__global__ __launch_bounds__(256) void k_kvpart(const unsigned short* __restrict__ kT,
                                                const unsigned short* __restrict__ vT,
                                                float* __restrict__ kvp,
                                                float* __restrict__ sumkp) {
  __shared__ unsigned short Ks[64 * 64];
  __shared__ unsigned short Vs[64 * 64];
  const int blk = blockIdx.x;
  const int bh = blk >> 3, ch = blk & 7;
  const int tid = threadIdx.x, lane = tid & 63, wave = tid >> 6;
  const unsigned short* kb = kT + (size_t)bh * 64 * 4096;
  const unsigned short* vb = vT + (size_t)bh * 64 * 4096;
  const int n0 = ch * 512;
  // staging: thread slot = lane*16B within chunk c*1024B -> row = c*8 + (lane>>3),
  // col = (lane&7)*16B; pre-swizzled source col (row&7 = lane>>3):
  const int lrow = lane >> 3;
  const int lcolz = (((lane & 7) ^ (lane >> 3)) << 3);
  f32x4 acc[5] = {};

  // ones-column fragment: B[k][0]=1 for all k -> lanes with (lane&15)==0 hold 1.0
  bf16x8 ones_frag;
  {
    unsigned short o = ((lane & 15) == 0) ? (unsigned short)0x3F80 : (unsigned short)0;
    union { unsigned short u[8]; bf16x8 v; } c;
#pragma unroll
    for (int i = 0; i < 8; ++i) c.u[i] = o;
    ones_frag = c.v;
  }

  // swizzled read col offsets (elems) for kk=0/1: (kk*32 + (lane>>4)*8) ^ ((lane&7)*8)
  const int rxor = (lane & 7) << 3;
  const int col0 = (((lane >> 4) << 3)) ^ rxor;
  const int col1 = ((32 + ((lane >> 4) << 3))) ^ rxor;

  for (int ks = 0; ks < 512; ks += 64) {
    __syncthreads();
#pragma unroll
    for (int i = 0; i < 2; ++i) {
      const int c = i * 4 + wave;
      gload_lds16(kb + (size_t)(c * 8 + lrow) * 4096 + n0 + ks + lcolz, &Ks[c * 512]);
      gload_lds16(vb + (size_t)(c * 8 + lrow) * 4096 + n0 + ks + lcolz, &Vs[c * 512]);
    }
    __syncthreads();
    const int ar = wave * 16 + (lane & 15);
#pragma unroll
    for (int kk = 0; kk < 2; ++kk) {
      const int co = kk ? col1 : col0;
      bf16x8 a = *(const bf16x8*)&Ks[ar * 64 + co];
#pragma unroll
      for (int n = 0; n < 4; ++n) {
        bf16x8 bv = *(const bf16x8*)&Vs[(n * 16 + (lane & 15)) * 64 + co];
        acc[n] = mfma16(a, bv, acc[n]);
      }
      acc[4] = mfma16(a, ones_frag, acc[4]);
    }
  }
  float* dst = kvp + (size_t)blk * 64 * 64;
  const int d0 = wave * 16 + ((lane >> 4) << 2);
#pragma unroll
  for (int n = 0; n < 4; ++n)
#pragma unroll
    for (int i = 0; i < 4; ++i)
      dst[(d0 + i) * 64 + n * 16 + (lane & 15)] = acc[n][i];
  if ((lane & 15) == 0) {
#pragma unroll
    for (int i = 0; i < 4; ++i) sumkp[(size_t)blk * 64 + d0 + i] = acc[4][i];
  }
}

// ---------------- kv reduce: sum 8 partials, write B^T panel [80][64] per bh -----------

__global__ __launch_bounds__(256) void k_kvred(const float* __restrict__ kvp,
                                               const float* __restrict__ sumkp,
                                               unsigned short* __restrict__ kvsk) {
  const int bh = blockIdx.x, tid = threadIdx.x;
  const float* src = kvp + (size_t)bh * 8 * 4096;
  unsigned short* dst = kvsk + (size_t)bh * 80 * 64;
#pragma unroll
  for (int it = 0; it < 16; ++it) {
    const int idx = tid + it * 256;
    const int e = idx >> 6, d = idx & 63;
    float s = 0.f;
#pragma unroll
    for (int c = 0; c < 8; ++c) s += src[c * 4096 + d * 64 + e];
    dst[idx] = f2bf(s);
  }
#pragma unroll
  for (int it = 0; it < 4; ++it) {
    const int idx = tid + it * 256;
    const int e2 = idx >> 6, d = idx & 63;
    float v = 0.f;
    if (e2 == 0) {
#pragma unroll
      for (int c = 0; c < 8; ++c) v += sumkp[(size_t)(bh * 8 + c) * 64 + d];
    }
    dst[64 * 64 + idx] = f2bf(v);
  }
}

// ---------------- numerator/denominator/divide ----------------
// Bs[80 rows][64 elems] = 128B rows, swizzled on write + read: byte ^= ((row&7)<<4).

__global__ __launch_bounds__(256) void k_numer(const unsigned short* __restrict__ qb,
                                               const unsigned short* __restrict__ kvsk,
                                               unsigned short* __restrict__ yb) {
  __shared__ unsigned short Bs[80 * 64];
  const int bh = blockIdx.y;
  const int b = bh >> 4, h = bh & 15;
  const int n0 = blockIdx.x << 7;
  const int tid = threadIdx.x, lane = tid & 63, wave = tid >> 6;
  {
    const uint4* src = (const uint4*)(kvsk + (size_t)bh * 80 * 64);
    uint4* dst = (uint4*)Bs;
    for (int i = tid; i < 640; i += 256) dst[i ^ ((i >> 3) & 7)] = src[i];
  }
  __syncthreads();

  const int ko = (lane >> 4) << 3;
  const int rx = (lane & 7) << 3;
  f32x4 acc[2][5] = {};
  const unsigned short* qrow =
      qb + (size_t)(b * 4096 + n0 + wave * 32 + (lane & 15)) * 1024 + h * 64;
#pragma unroll
  for (int kk = 0; kk < 2; ++kk) {
    bf16x8 a[2], bb[5];
#pragma unroll
    for (int m = 0; m < 2; ++m)
      a[m] = *(const bf16x8*)(qrow + (size_t)m * 16 * 1024 + ko + kk * 32);
#pragma unroll
    for (int n = 0; n < 5; ++n)
      bb[n] = *(const bf16x8*)&Bs[(n * 16 + (lane & 15)) * 64 + ((ko + kk * 32) ^ rx)];
#pragma unroll
    for (int m = 0; m < 2; ++m)
#pragma unroll
      for (int n = 0; n < 5; ++n)
        acc[m][n] = mfma16(a[m], bb[n], acc[m][n]);
  }

  const int rbase = b * 4096 + n0 + wave * 32 + ((lane >> 4) << 2);
#pragma unroll
  for (int m = 0; m < 2; ++m) {
    f32x4 inv;
#pragma unroll
    for (int i = 0; i < 4; ++i) {
      float den = __shfl(acc[m][4][i], lane & 48);
      inv[i] = __builtin_amdgcn_rcpf(den);
    }
#pragma unroll
    for (int n = 0; n < 4; ++n) {
      const int col = h * 64 + n * 16 + (lane & 15);
#pragma unroll
      for (int i = 0; i < 4; ++i)
        yb[(size_t)(rbase + m * 16 + i) * 1024 + col] = f2bf(acc[m][n][i] * inv[i]);
    }
  }
}

// ---------------- launch ----------------

extern "C" void kernel_launch(void* const* d_in, const int* in_sizes, int n_in,
                              void* d_out, int out_size, void* d_ws, size_t ws_size,
                              hipStream_t stream) {
  const float* x = (const float*)d_in[0];
  const float* w_qkv = (const float*)d_in[1];
  const float* w_proj = (const float*)d_in[2];
  const float* b_proj = (const float*)d_in[3];
  float* out = (float*)d_out;
  char* ws = (char*)d_ws;

  unsigned short* xb = (unsigned short*)(ws);                   // 33,554,432 B (reused as yb)
  unsigned short* wqkvT = (unsigned short*)(ws + 33554432);     //  6,291,456 B (reused as sumkp)
  unsigned short* wprojT = (unsigned short*)(ws + 39845888);    //  2,097,152 B
  unsigned short* qb = (unsigned short*)(ws + 41943040);        // 33,554,432 B
  unsigned short* kT = (unsigned short*)(ws + 75497472);        // 33,554,432 B
  unsigned short* vT = (unsigned short*)(ws + 109051904);       // 33,554,432 B
  float* kvp = (float*)(ws + 142606336);                        //  8,388,608 B
  unsigned short* kvsk = (unsigned short*)(ws + 151011328);     //    655,360 B
  unsigned short* yb = xb;                 // xb dead after GEMM1
  float* sumkp = (float*)wqkvT;            // wqkvT dead after GEMM1 (512*64*4 = 131072 B)

  k_cvt_x<<<2048, 256, 0, stream>>>(x, xb, 4 * 4096 * 1024);
  k_cvt_t<<<dim3(96, 32), 256, 0, stream>>>(w_qkv, wqkvT, 1024, 3072);
  k_cvt_t<<<dim3(32, 32), 256, 0, stream>>>(w_proj, wprojT, 1024, 1024);
  k_gemm256<0><<<768, 512, 131072, stream>>>(xb, wqkvT, 12, qb, kT, vT, nullptr, nullptr);
  k_kvpart<<<512, 256, 0, stream>>>(kT, vT, kvp, sumkp);
  k_kvred<<<64, 256, 0, stream>>>(kvp, sumkp, kvsk);
  k_numer<<<dim3(32, 64), 256, 0, stream>>>(qb, kvsk, yb);
  k_gemm256<1><<<256, 512, 131072, stream>>>(yb, wprojT, 4, nullptr, nullptr, nullptr,
                                             b_proj, out);
}

// Round 4
// 221.234 us; speedup vs baseline: 1.3595x; 1.0072x over previous
//
#include <hip/hip_runtime.h>

typedef __bf16 bf16x8 __attribute__((ext_vector_type(8)));
typedef float f32x4 __attribute__((ext_vector_type(4)));

typedef const unsigned int __attribute__((address_space(1)))* gas_p;
typedef unsigned int __attribute__((address_space(3)))* las_p;

__device__ __forceinline__ void gload_lds16(const void* g, void* l) {
  __builtin_amdgcn_global_load_lds((gas_p)g, (las_p)l, 16, 0, 0);
}

__device__ __forceinline__ unsigned short f2bf(float f) {
  union { float f; unsigned int u; } x; x.f = f;
  unsigned int r = x.u + 0x7fffu + ((x.u >> 16) & 1u);
  return (unsigned short)(r >> 16);
}
__device__ __forceinline__ float elu1(float x) {
  return x > 0.f ? x + 1.f : __expf(x);
}
__device__ __forceinline__ f32x4 mfma16(bf16x8 a, bf16x8 b, f32x4 c) {
  return __builtin_amdgcn_mfma_f32_16x16x32_bf16(a, b, c, 0, 0, 0);
}

#define BAR() __builtin_amdgcn_s_barrier()
#define VMW8() asm volatile("s_waitcnt vmcnt(8)" ::: "memory")
#define VMW4() asm volatile("s_waitcnt vmcnt(4)" ::: "memory")
#define VMW0() asm volatile("s_waitcnt vmcnt(0)" ::: "memory")

// ---------------- converts ----------------

__global__ __launch_bounds__(256) void k_cvt_x(const float* __restrict__ x,
                                               unsigned short* __restrict__ xb, int n) {
  int i = (blockIdx.x * 256 + threadIdx.x) * 4;
  const int stride = gridDim.x * 256 * 4;
  for (; i < n; i += stride) {
    float4 v = *(const float4*)(x + i);
    union { unsigned short u[4]; uint2 q; } pk;
    pk.u[0] = f2bf(v.x); pk.u[1] = f2bf(v.y); pk.u[2] = f2bf(v.z); pk.u[3] = f2bf(v.w);
    *(uint2*)(xb + i) = pk.q;
  }
}

__global__ __launch_bounds__(256) void k_cvt_t(const float* __restrict__ w,
                                               unsigned short* __restrict__ wT,
                                               int R, int Cc) {
  __shared__ float t[32][33];
  const int j0 = blockIdx.x * 32, i0 = blockIdx.y * 32;
  const int tx = threadIdx.x & 31, ty = threadIdx.x >> 5;
#pragma unroll
  for (int k = 0; k < 4; ++k)
    t[ty + 8 * k][tx] = w[(size_t)(i0 + ty + 8 * k) * Cc + j0 + tx];
  __syncthreads();
#pragma unroll
  for (int k = 0; k < 4; ++k)
    wT[(size_t)(j0 + ty + 8 * k) * R + i0 + tx] = f2bf(t[tx][ty + 8 * k]);
}

// ---------------- 256x256 GEMM, ring-4 half-pair deep pipeline -------------------------
// LDS: 4 slots per operand, slot = [256 rows][32 K-elems] (64B rows), 16 KiB each.
// pair g = 2*tile + kk lives in slot g&3. During tile t: P0/P1 stage pair 2t+3
// (= tile t+1, h1), P2/P3 stage pair 2t+4 (= tile t+2, h0). vmcnt(8) once per pair.
// Swizzle: col_bytes ^= ((row>>1)&3)<<4 on read; inverse-swizzled global source (rule 21).

template <int EPI>
__global__ __launch_bounds__(512, 2) void k_gemm256(
    const unsigned short* __restrict__ A, const unsigned short* __restrict__ BT, int NBX,
    unsigned short* __restrict__ qb, unsigned short* __restrict__ kT,
    unsigned short* __restrict__ vT, const float* __restrict__ bias,
    float* __restrict__ out) {
  extern __shared__ unsigned short lds[];
  unsigned short* Asb = lds;           // 4 slots x 8192 elems
  unsigned short* Bsb = lds + 32768;

  const int tid = threadIdx.x, lane = tid & 63, wave = tid >> 6;
  const int wm = wave >> 2, wn = wave & 3;
  int bid = blockIdx.x;
  { const int cpx = (int)gridDim.x >> 3; bid = (bid & 7) * cpx + (bid >> 3); }
  const int bx = bid % NBX, by = bid / NBX;
  const size_t bm0 = (size_t)by << 8, bn0 = (size_t)bx << 8;

  // staging: thread covers LDS row = wave*16 + lane/4, col = (lane&3)*8 within a slot.
  const int srow = (wave << 4) + (lane >> 2);
  const int gscol = ((lane & 3) << 3) ^ (((srow >> 1) & 3) << 3);
  const unsigned short* Ag0 = A + (bm0 + srow) * 1024 + gscol;
  const unsigned short* Bg0 = BT + (bn0 + srow) * 1024 + gscol;
  const int lws = wave << 9;

  auto stageA = [&](int slot, int kt, int kh) {
    const unsigned short* g_ = Ag0 + (kt << 6) + (kh << 5);
    unsigned short* l_ = Asb + (slot << 13) + lws;
    gload_lds16(g_, l_);
    gload_lds16(g_ + 128 * 1024, l_ + 4096);
  };
  auto stageB = [&](int slot, int kt, int kh) {
    const unsigned short* g_ = Bg0 + (kt << 6) + (kh << 5);
    unsigned short* l_ = Bsb + (slot << 13) + lws;
    gload_lds16(g_, l_);
    gload_lds16(g_ + 128 * 1024, l_ + 4096);
  };

  // fragment reads: swizzled k-offset within 32-elem window
  const int q8 = ((lane >> 4) << 3) ^ (((lane >> 1) & 3) << 3);
  const int ar_base = (wm << 7) + (lane & 15);
  const int br_base = (wn << 6) + (lane & 15);

  f32x4 acc[8][4] = {};  // [rh*4+mi][n]

  // prologue: stage pairs 0,1,2 (A,B interleaved -> in-order drain completes pair 0 first)
  stageA(0, 0, 0); stageB(0, 0, 0);
  stageA(1, 0, 1); stageB(1, 0, 1);
  stageA(2, 1, 0); stageB(2, 1, 0);
  VMW8();  // pair 0 landed
  BAR();

#pragma unroll
  for (int t = 0; t < 16; ++t) {
    const int s0 = (2 * t) & 3, s1 = (2 * t + 1) & 3;
    const int sA = (2 * t + 3) & 3, sB = (2 * t + 4) & 3;
    const int t1 = t + 1, t2 = (t + 2 > 15) ? 15 : t + 2;
    bf16x8 af[4], bfr[4];

    // ---- P0: pair s0, rh=0 (+ stage A(t+1,h1)) ----
#pragma unroll
    for (int mi = 0; mi < 4; ++mi)
      af[mi] = *(const bf16x8*)&Asb[(s0 << 13) + ((ar_base + mi * 16) << 5) + q8];
#pragma unroll
    for (int n = 0; n < 4; ++n)
      bfr[n] = *(const bf16x8*)&Bsb[(s0 << 13) + ((br_base + n * 16) << 5) + q8];
    if (t < 15) stageA(sA, t1, 1);
    BAR();
    __builtin_amdgcn_s_setprio(1);
#pragma unroll
    for (int mi = 0; mi < 4; ++mi)
#pragma unroll
      for (int n = 0; n < 4; ++n) acc[mi][n] = mfma16(af[mi], bfr[n], acc[mi][n]);
    __builtin_amdgcn_s_setprio(0);
    BAR();

    // ---- P1: pair s0, rh=1 (+ stage B(t+1,h1)) ----
#pragma unroll
    for (int mi = 0; mi < 4; ++mi)
      af[mi] = *(const bf16x8*)&Asb[(s0 << 13) + ((ar_base + 64 + mi * 16) << 5) + q8];
    if (t < 15) stageB(sA, t1, 1);
    BAR();
    __builtin_amdgcn_s_setprio(1);
#pragma unroll
    for (int mi = 0; mi < 4; ++mi)
#pragma unroll
      for (int n = 0; n < 4; ++n) acc[4 + mi][n] = mfma16(af[mi], bfr[n], acc[4 + mi][n]);
    __builtin_amdgcn_s_setprio(0);
    if (t < 15) { VMW8(); } else { VMW4(); }  // pair 2t+1 landed
    BAR();

    // ---- P2: pair s1, rh=0 (+ stage A(t+2,h0)) ----
#pragma unroll
    for (int mi = 0; mi < 4; ++mi)
      af[mi] = *(const bf16x8*)&Asb[(s1 << 13) + ((ar_base + mi * 16) << 5) + q8];
#pragma unroll
    for (int n = 0; n < 4; ++n)
      bfr[n] = *(const bf16x8*)&Bsb[(s1 << 13) + ((br_base + n * 16) << 5) + q8];
    if (t < 15) stageA(sB, t2, 0);
    BAR();
    __builtin_amdgcn_s_setprio(1);
#pragma unroll
    for (int mi = 0; mi < 4; ++mi)
#pragma unroll
      for (int n = 0; n < 4; ++n) acc[mi][n] = mfma16(af[mi], bfr[n], acc[mi][n]);
    __builtin_amdgcn_s_setprio(0);
    BAR();

    // ---- P3: pair s1, rh=1 (+ stage B(t+2,h0)) ----
#pragma unroll
    for (int mi = 0; mi < 4; ++mi)
      af[mi] = *(const bf16x8*)&Asb[(s1 << 13) + ((ar_base + 64 + mi * 16) << 5) + q8];
    if (t < 15) stageB(sB, t2, 0);
    BAR();
    __builtin_amdgcn_s_setprio(1);
#pragma unroll
    for (int mi = 0; mi < 4; ++mi)
#pragma unroll
      for (int n = 0; n < 4; ++n) acc[4 + mi][n] = mfma16(af[mi], bfr[n], acc[4 + mi][n]);
    __builtin_amdgcn_s_setprio(0);
    if (t < 15) VMW8();  // pair 2t+2 landed
    BAR();
  }
  VMW0();  // drain leftover stages before epilogue/endpgm

  // ---- epilogue ----
  const int rbase = (int)bm0 + (wm << 7) + ((lane >> 4) << 2);
  const int cbase = (int)bn0 + (wn << 6) + (lane & 15);
  if constexpr (EPI == 0) {
    const int reg3 = (int)(bn0 >> 10);  // 0=q 1=k 2=v, uniform per block
#pragma unroll
    for (int m = 0; m < 8; ++m) {
      const int rb = rbase + m * 16;
#pragma unroll
      for (int n = 0; n < 4; ++n) {
        const int col = cbase + n * 16;
        if (reg3 == 0) {
#pragma unroll
          for (int i = 0; i < 4; ++i)
            qb[(size_t)(rb + i) * 1024 + col] = f2bf(elu1(acc[m][n][i]));
        } else {
          const int jc = col & 1023, h = jc >> 6, d = jc & 63;
          const int b_ = rb >> 12, n_ = rb & 4095;
          union { unsigned short u[4]; uint2 q; } pk;
          if (reg3 == 1) {
#pragma unroll
            for (int i = 0; i < 4; ++i) pk.u[i] = f2bf(elu1(acc[m][n][i]));
          } else {
#pragma unroll
            for (int i = 0; i < 4; ++i) pk.u[i] = f2bf(acc[m][n][i]);
          }
          unsigned short* dst = (reg3 == 1) ? kT : vT;
          *(uint2*)(dst + ((size_t)((b_ * 16 + h) * 64 + d) * 4096 + n_)) = pk.q;
        }
      }
    }
  } else {
#pragma unroll
    for (int n = 0; n < 4; ++n) {
      const int col = cbase + n * 16;
      const float bc = bias[col];
#pragma unroll
      for (int m = 0; m < 8; ++m) {
        const int rb = rbase + m * 16;
#pragma unroll
        for (int i = 0; i < 4; ++i)
          out[(size_t)(rb + i) * 1024 + col] = acc[m][n][i] + bc;
      }
    }
  }
}

// ---------------- kv partial (+ fused sum_k via ones-column) ----------------
// LDS tiles [64 rows][64 elems] = 128B rows; swizzle byte ^= ((row&7)<<4).

__global__ __launch_bounds__(256) void k_kvpart(const unsigned short* __restrict__ kT,
                                                const unsigned short* __restrict__ vT,
                                                float* __restrict__ kvp,
                                                float* __restrict__ sumkp) {
  __shared__ unsigned short Ks[64 * 64];
  __shared__ unsigned short Vs[64 * 64];
  const int blk = blockIdx.x;
  const int bh = blk >> 3, ch = blk & 7;
  const int tid = threadIdx.x, lane = tid & 63, wave = tid >> 6;
  const unsigned short* kb = kT + (size_t)bh * 64 * 4096;
  const unsigned short* vb = vT + (size_t)bh * 64 * 4096;
  const int n0 = ch * 512;
  const int lrow = lane >> 3;
  const int lcolz = (((lane & 7) ^ (lane >> 3)) << 3);
  f32x4 acc[5] = {};

  bf16x8 ones_frag;
  {
    unsigned short o = ((lane & 15) == 0) ? (unsigned short)0x3F80 : (unsigned short)0;
    union { unsigned short u[8]; bf16x8 v; } c;
#pragma unroll
    for (int i = 0; i < 8; ++i) c.u[i] = o;
    ones_frag = c.v;
  }

  const int rxor = (lane & 7) << 3;
  const int col0 = (((lane >> 4) << 3)) ^ rxor;
  const int col1 = ((32 + ((lane >> 4) << 3))) ^ rxor;

  for (int ks = 0; ks < 512; ks += 64) {
    __syncthreads();
#pragma unroll
    for (int i = 0; i < 2; ++i) {
      const int c = i * 4 + wave;
      gload_lds16(kb + (size_t)(c * 8 + lrow) * 4096 + n0 + ks + lcolz, &Ks[c * 512]);
      gload_lds16(vb + (size_t)(c * 8 + lrow) * 4096 + n0 + ks + lcolz, &Vs[c * 512]);
    }
    __syncthreads();
    const int ar = wave * 16 + (lane & 15);
#pragma unroll
    for (int kk = 0; kk < 2; ++kk) {
      const int co = kk ? col1 : col0;
      bf16x8 a = *(const bf16x8*)&Ks[ar * 64 + co];
#pragma unroll
      for (int n = 0; n < 4; ++n) {
        bf16x8 bv = *(const bf16x8*)&Vs[(n * 16 + (lane & 15)) * 64 + co];
        acc[n] = mfma16(a, bv, acc[n]);
      }
      acc[4] = mfma16(a, ones_frag, acc[4]);
    }
  }
  float* dst = kvp + (size_t)blk * 64 * 64;
  const int d0 = wave * 16 + ((lane >> 4) << 2);
#pragma unroll
  for (int n = 0; n < 4; ++n)
#pragma unroll
    for (int i = 0; i < 4; ++i)
      dst[(d0 + i) * 64 + n * 16 + (lane & 15)] = acc[n][i];
  if ((lane & 15) == 0) {
#pragma unroll
    for (int i = 0; i < 4; ++i) sumkp[(size_t)blk * 64 + d0 + i] = acc[4][i];
  }
}

// ---------------- kv reduce: sum 8 partials, write B^T panel [80][64] per bh -----------

__global__ __launch_bounds__(256) void k_kvred(const float* __restrict__ kvp,
                                               const float* __restrict__ sumkp,
                                               unsigned short* __restrict__ kvsk) {
  const int bh = blockIdx.x, tid = threadIdx.x;
  const float* src = kvp + (size_t)bh * 8 * 4096;
  unsigned short* dst = kvsk + (size_t)bh * 80 * 64;
#pragma unroll
  for (int it = 0; it < 16; ++it) {
    const int idx = tid + it * 256;
    const int e = idx >> 6, d = idx & 63;
    float s = 0.f;
#pragma unroll
    for (int c = 0; c < 8; ++c) s += src[c * 4096 + d * 64 + e];
    dst[idx] = f2bf(s);
  }
#pragma unroll
  for (int it = 0; it < 4; ++it) {
    const int idx = tid + it * 256;
    const int e2 = idx >> 6, d = idx & 63;
    float v = 0.f;
    if (e2 == 0) {
#pragma unroll
      for (int c = 0; c < 8; ++c) v += sumkp[(size_t)(bh * 8 + c) * 64 + d];
    }
    dst[64 * 64 + idx] = f2bf(v);
  }
}

// ---------------- numerator/denominator/divide ----------------
// Bs[80 rows][64 elems] = 128B rows, swizzled on write + read: byte ^= ((row&7)<<4).

__global__ __launch_bounds__(256) void k_numer(const unsigned short* __restrict__ qb,
                                               const unsigned short* __restrict__ kvsk,
                                               unsigned short* __restrict__ yb) {
  __shared__ unsigned short Bs[80 * 64];
  const int bh = blockIdx.y;
  const int b = bh >> 4, h = bh & 15;
  const int n0 = blockIdx.x << 7;
  const int tid = threadIdx.x, lane = tid & 63, wave = tid >> 6;
  {
    const uint4* src = (const uint4*)(kvsk + (size_t)bh * 80 * 64);
    uint4* dst = (uint4*)Bs;
    for (int i = tid; i < 640; i += 256) dst[i ^ ((i >> 3) & 7)] = src[i];
  }
  __syncthreads();

  const int ko = (lane >> 4) << 3;
  const int rx = (lane & 7) << 3;
  f32x4 acc[2][5] = {};
  const unsigned short* qrow =
      qb + (size_t)(b * 4096 + n0 + wave * 32 + (lane & 15)) * 1024 + h * 64;
#pragma unroll
  for (int kk = 0; kk < 2; ++kk) {
    bf16x8 a[2], bb[5];
#pragma unroll
    for (int m = 0; m < 2; ++m)
      a[m] = *(const bf16x8*)(qrow + (size_t)m * 16 * 1024 + ko + kk * 32);
#pragma unroll
    for (int n = 0; n < 5; ++n)
      bb[n] = *(const bf16x8*)&Bs[(n * 16 + (lane & 15)) * 64 + ((ko + kk * 32) ^ rx)];
#pragma unroll
    for (int m = 0; m < 2; ++m)
#pragma unroll
      for (int n = 0; n < 5; ++n)
        acc[m][n] = mfma16(a[m], bb[n], acc[m][n]);
  }

  const int rbase = b * 4096 + n0 + wave * 32 + ((lane >> 4) << 2);
#pragma unroll
  for (int m = 0; m < 2; ++m) {
    f32x4 inv;
#pragma unroll
    for (int i = 0; i < 4; ++i) {
      float den = __shfl(acc[m][4][i], lane & 48);
      inv[i] = __builtin_amdgcn_rcpf(den);
    }
#pragma unroll
    for (int n = 0; n < 4; ++n) {
      const int col = h * 64 + n * 16 + (lane & 15);
#pragma unroll
      for (int i = 0; i < 4; ++i)
        yb[(size_t)(rbase + m * 16 + i) * 1024 + col] = f2bf(acc[m][n][i] * inv[i]);
    }
  }
}

// ---------------- launch ----------------

extern "C" void kernel_launch(void* const* d_in, const int* in_sizes, int n_in,
                              void* d_out, int out_size, void* d_ws, size_t ws_size,
                              hipStream_t stream) {
  const float* x = (const float*)d_in[0];
  const float* w_qkv = (const float*)d_in[1];
  const float* w_proj = (const float*)d_in[2];
  const float* b_proj = (const float*)d_in[3];
  float* out = (float*)d_out;
  char* ws = (char*)d_ws;

  unsigned short* xb = (unsigned short*)(ws);                   // 33,554,432 B (reused as yb)
  unsigned short* wqkvT = (unsigned short*)(ws + 33554432);     //  6,291,456 B (reused as sumkp)
  unsigned short* wprojT = (unsigned short*)(ws + 39845888);    //  2,097,152 B
  unsigned short* qb = (unsigned short*)(ws + 41943040);        // 33,554,432 B
  unsigned short* kT = (unsigned short*)(ws + 75497472);        // 33,554,432 B
  unsigned short* vT = (unsigned short*)(ws + 109051904);       // 33,554,432 B
  float* kvp = (float*)(ws + 142606336);                        //  8,388,608 B
  unsigned short* kvsk = (unsigned short*)(ws + 151011328);     //    655,360 B
  unsigned short* yb = xb;                 // xb dead after GEMM1
  float* sumkp = (float*)wqkvT;            // wqkvT dead after GEMM1 (512*64*4 = 131072 B)

  k_cvt_x<<<2048, 256, 0, stream>>>(x, xb, 4 * 4096 * 1024);
  k_cvt_t<<<dim3(96, 32), 256, 0, stream>>>(w_qkv, wqkvT, 1024, 3072);
  k_cvt_t<<<dim3(32, 32), 256, 0, stream>>>(w_proj, wprojT, 1024, 1024);
  k_gemm256<0><<<768, 512, 131072, stream>>>(xb, wqkvT, 12, qb, kT, vT, nullptr, nullptr);
  k_kvpart<<<512, 256, 0, stream>>>(kT, vT, kvp, sumkp);
  k_kvred<<<64, 256, 0, stream>>>(kvp, sumkp, kvsk);
  k_numer<<<dim3(32, 64), 256, 0, stream>>>(qb, kvsk, yb);
  k_gemm256<1><<<256, 512, 131072, stream>>>(yb, wprojT, 4, nullptr, nullptr, nullptr,
                                             b_proj, out);
}